// Round 2
// baseline (683.452 us; speedup 1.0000x reference)
//
#include <hip/hip_runtime.h>

// Sparse UNet, fp16-feature version.
// conv kernels: pure gather + v_dot2_f32_f16 contraction (BN/ReLU hoisted out),
// fp16 weights pre-transposed to [k][d][c] in LDS (28KB -> 4-5 blocks/CU).
// BN applied in a separate streaming pass (pre-BN fp16 -> post-BN fp16).
// Head is linear => per-batch channel sums of h3 only.

#define DEVI __device__ __forceinline__

typedef _Float16 h2 __attribute__((ext_vector_type(2)));

constexpr int KNBR = 27;

DEVI h2 bch2(unsigned u) { return __builtin_bit_cast(h2, u); }
DEVI unsigned pkh2(float a, float b) {
    h2 v; v.x = (_Float16)a; v.y = (_Float16)b;
    return __builtin_bit_cast(unsigned, v);
}
DEVI float bnr(float x, float sc, float sh) {
    float y = fmaf(x, sc, sh);
    return y > 0.f ? y : 0.f;
}

// ---------------- prep ----------------

// block 0..2: transpose+convert W_b (fp32 [k][c][d]) -> fp16 [k][d][c_pad]
// block 3: zero bsum
__global__ __launch_bounds__(256)
void prep_weights_kernel(const float* __restrict__ W1, const float* __restrict__ W2,
                         const float* __restrict__ W3,
                         _Float16* __restrict__ w1t, _Float16* __restrict__ w2t,
                         _Float16* __restrict__ w3t,
                         float* __restrict__ bsum, int nb)
{
    const int b = blockIdx.x;
    if (b == 3) {
        for (int i = threadIdx.x; i < nb; i += 256) bsum[i] = 0.f;
        return;
    }
    const float* W = (b == 0) ? W1 : (b == 1) ? W2 : W3;
    _Float16* dst   = (b == 0) ? w1t : (b == 1) ? w2t : w3t;
    const int CINs = (b == 0) ? 6 : (b == 1) ? 16 : 32;
    const int CINp = (b == 0) ? 8 : CINs;
    const int CO   = (b == 1) ? 32 : 16;
    const int total = KNBR * CO * CINp;
    for (int i = threadIdx.x; i < total; i += 256) {
        const int c = i % CINp;
        const int d = (i / CINp) % CO;
        const int k = i / (CINp * CO);
        const float v = (c < CINs) ? W[(k * CINs + c) * CO + d] : 0.f;
        dst[i] = (_Float16)v;
    }
}

// fp32 [N][6] -> fp16 [N+1][8] (pad channels, zero row N)
__global__ __launch_bounds__(256)
void prep_feats_kernel(const float* __restrict__ f0, const float* __restrict__ f1,
                       _Float16* __restrict__ o, int N)
{
    const int s = blockIdx.y;
    const float* __restrict__ f = s ? f1 : f0;
    _Float16* __restrict__ out = o + (size_t)s * (N + 1) * 8;
    const int n = blockIdx.x * 256 + threadIdx.x;
    if (n < N) {
        const float2* r = (const float2*)(f + (size_t)n * 6);
        float2 a = r[0], b = r[1], c = r[2];
        uint4 w;
        w.x = pkh2(a.x, a.y);
        w.y = pkh2(b.x, b.y);
        w.z = pkh2(c.x, c.y);
        w.w = 0u;
        ((uint4*)out)[n] = w;
    } else if (n == N) {
        ((uint4*)out)[n] = make_uint4(0u, 0u, 0u, 0u);
    }
}

// ---------------- conv (gather + dot2) ----------------

template<int CIN, int COUT>
__global__ __launch_bounds__(256)
void conv_kernel(const _Float16* __restrict__ feats,   // [2][(N+1)*CIN] post-BN fp16
                 const int* __restrict__ nb0, const int* __restrict__ nb1,
                 const _Float16* __restrict__ Wt,      // [27*COUT*CIN] fp16 [k][d][c]
                 _Float16* __restrict__ outp,          // [2][(N+1)*COUT] pre-BN fp16
                 float* __restrict__ partials,
                 int N, int nblk)
{
    constexpr int C8 = CIN / 8;
    const int s = blockIdx.y;
    const _Float16* __restrict__ fs = feats + (size_t)s * (N + 1) * CIN;
    const int* __restrict__ nbr = s ? nb1 : nb0;
    _Float16* __restrict__ out = outp + (size_t)s * (N + 1) * COUT;

    __shared__ __align__(16) _Float16 wl[KNBR * COUT * CIN];
    __shared__ float sred[4][64];
    for (int i = threadIdx.x * 8; i < KNBR * COUT * CIN; i += 256 * 8)
        ((uint4*)wl)[i / 8] = ((const uint4*)Wt)[i / 8];
    __syncthreads();
    const uint4* wl4 = (const uint4*)wl;

    const int tid = threadIdx.x;
    const int n = blockIdx.x * 256 + tid;
    const bool act = n < N;

    float acc[COUT];
    #pragma unroll
    for (int d = 0; d < COUT; ++d) acc[d] = 0.f;

    int cidx = act ? nbr[(size_t)n * KNBR] : N;   // row N is zeros
    for (int k = 0; k < KNBR; ++k) {
        const int kn = (k + 1 < KNBR) ? (k + 1) : (KNBR - 1);
        const int nxt = act ? nbr[(size_t)n * KNBR + kn] : N;

        const uint4* rp = (const uint4*)(fs + (size_t)cidx * CIN);
        uint4 rw[C8];
        #pragma unroll
        for (int c8 = 0; c8 < C8; ++c8) rw[c8] = rp[c8];

        #pragma unroll
        for (int d = 0; d < COUT; ++d) {
            #pragma unroll
            for (int c8 = 0; c8 < C8; ++c8) {
                const uint4 wv = wl4[(k * COUT + d) * C8 + c8];
                acc[d] = __builtin_amdgcn_fdot2(bch2(rw[c8].x), bch2(wv.x), acc[d], false);
                acc[d] = __builtin_amdgcn_fdot2(bch2(rw[c8].y), bch2(wv.y), acc[d], false);
                acc[d] = __builtin_amdgcn_fdot2(bch2(rw[c8].z), bch2(wv.z), acc[d], false);
                acc[d] = __builtin_amdgcn_fdot2(bch2(rw[c8].w), bch2(wv.w), acc[d], false);
            }
        }
        cidx = nxt;
    }

    if (act) {
        unsigned ow[COUT / 2];
        #pragma unroll
        for (int d2 = 0; d2 < COUT / 2; ++d2) ow[d2] = pkh2(acc[2 * d2], acc[2 * d2 + 1]);
        uint4* orow = (uint4*)(out + (size_t)n * COUT);
        #pragma unroll
        for (int q = 0; q < COUT / 8; ++q)
            orow[q] = make_uint4(ow[4 * q], ow[4 * q + 1], ow[4 * q + 2], ow[4 * q + 3]);
    }

    // BN statistics: per-thread (sum, sumsq) -> wave butterfly -> block -> partials
    float ts[COUT], tq[COUT];
    #pragma unroll
    for (int d = 0; d < COUT; ++d) { ts[d] = acc[d]; tq[d] = acc[d] * acc[d]; }
    #pragma unroll
    for (int d = 0; d < COUT; ++d) {
        #pragma unroll
        for (int m = 32; m >= 1; m >>= 1) {
            ts[d] += __shfl_xor(ts[d], m);
            tq[d] += __shfl_xor(tq[d], m);
        }
    }
    const int lane = tid & 63;
    const int wid = tid >> 6;
    if (lane == 0) {
        #pragma unroll
        for (int d = 0; d < COUT; ++d) {
            sred[wid][d] = ts[d];
            sred[wid][COUT + d] = tq[d];
        }
    }
    __syncthreads();
    if (tid < 2 * COUT) {
        float tot = sred[0][tid] + sred[1][tid] + sred[2][tid] + sred[3][tid];
        partials[((size_t)s * nblk + blockIdx.x) * 64 + tid] = tot;
    }
}

// ---------------- BN stats -> scale/shift ----------------

template<int COUT>
__global__ __launch_bounds__(256)
void stats_kernel(const float* __restrict__ partials, int nblk, int N,
                  const float* __restrict__ g, const float* __restrict__ b,
                  float* __restrict__ ss)
{
    const int s = blockIdx.y;
    const int tid = threadIdx.x;
    const float* P = partials + (size_t)s * nblk * 64;
    const int q = tid & 63;
    const int ch = tid >> 6;
    float a = 0.f;
    for (int i = ch; i < nblk; i += 4) a += P[(size_t)i * 64 + q];
    __shared__ float red[256];
    red[tid] = a;
    __syncthreads();
    if (tid < 64) red[tid] = red[tid] + red[64 + tid] + red[128 + tid] + red[192 + tid];
    __syncthreads();
    if (tid < COUT) {
        float sum = red[tid];
        float sq = red[COUT + tid];
        float mean = sum / (float)N;
        float var = sq / (float)N - mean * mean;
        float scl = g[tid] * rsqrtf(var + 1e-4f);
        float sft = b[tid] - mean * scl;
        float* ssp = ss + s * 64;
        ssp[tid] = scl;
        ssp[32 + tid] = sft;
    }
}

// ---------------- apply BN+ReLU (streaming) ----------------

template<int COUT>
__global__ __launch_bounds__(256)
void apply_kernel(const _Float16* __restrict__ pre, _Float16* __restrict__ post,
                  const float* __restrict__ ss, int N)
{
    const int s = blockIdx.y;
    const _Float16* __restrict__ p = pre + (size_t)s * (N + 1) * COUT;
    _Float16* __restrict__ o = post + (size_t)s * (N + 1) * COUT;
    __shared__ float sc[32], sh[32];
    if (threadIdx.x < COUT) {
        sc[threadIdx.x] = ss[s * 64 + threadIdx.x];
        sh[threadIdx.x] = ss[s * 64 + 32 + threadIdx.x];
    }
    __syncthreads();
    const int chunks = (N + 1) * COUT / 8;
    const int i = blockIdx.x * 256 + threadIdx.x;
    if (i >= chunks) return;
    const int row = (i * 8) / COUT;
    const int cb = (i * 8) % COUT;
    uint4 v = ((const uint4*)p)[i];
    uint4 r;
    {
        h2 x0 = bch2(v.x), x1 = bch2(v.y), x2 = bch2(v.z), x3 = bch2(v.w);
        r.x = pkh2(bnr((float)x0.x, sc[cb + 0], sh[cb + 0]),
                   bnr((float)x0.y, sc[cb + 1], sh[cb + 1]));
        r.y = pkh2(bnr((float)x1.x, sc[cb + 2], sh[cb + 2]),
                   bnr((float)x1.y, sc[cb + 3], sh[cb + 3]));
        r.z = pkh2(bnr((float)x2.x, sc[cb + 4], sh[cb + 4]),
                   bnr((float)x2.y, sc[cb + 5], sh[cb + 5]));
        r.w = pkh2(bnr((float)x3.x, sc[cb + 6], sh[cb + 6]),
                   bnr((float)x3.y, sc[cb + 7], sh[cb + 7]));
    }
    if (row >= N) r = make_uint4(0u, 0u, 0u, 0u);
    ((uint4*)o)[i] = r;
}

// ---------------- point gather + per-batch channel sums (BN3 inline) ----------------

__global__ __launch_bounds__(256)
void pointsum_kernel(const _Float16* __restrict__ h3,  // [2][(N+1)*16] pre-BN fp16
                     const int* __restrict__ id0, const int* __restrict__ id1,
                     const float* __restrict__ ss, float* __restrict__ bsum,
                     int N, int Ppb, int bpb, int bs)
{
    const int s = blockIdx.y;
    const _Float16* __restrict__ h = h3 + (size_t)s * (N + 1) * 16;
    const int* __restrict__ ids = s ? id1 : id0;
    const int batch = blockIdx.x / bpb;
    const int blk = blockIdx.x % bpb;

    const float* ssp = ss + s * 64;
    float sc[16], sh[16];
    #pragma unroll
    for (int c = 0; c < 16; ++c) { sc[c] = ssp[c]; sh[c] = ssp[32 + c]; }

    float acc[16];
    #pragma unroll
    for (int c = 0; c < 16; ++c) acc[c] = 0.f;

    const int* bid = ids + (size_t)batch * Ppb;
    const int base = blk * (256 * 8) + threadIdx.x;
    for (int i = 0; i < 8; ++i) {
        int off = base + i * 256;
        if (off < Ppb) {
            int vx = bid[off];
            const uint4* r = (const uint4*)(h + (size_t)vx * 16);
            uint4 a = r[0], b = r[1];
            h2 x;
            x = bch2(a.x); acc[0] += bnr((float)x.x, sc[0], sh[0]);  acc[1] += bnr((float)x.y, sc[1], sh[1]);
            x = bch2(a.y); acc[2] += bnr((float)x.x, sc[2], sh[2]);  acc[3] += bnr((float)x.y, sc[3], sh[3]);
            x = bch2(a.z); acc[4] += bnr((float)x.x, sc[4], sh[4]);  acc[5] += bnr((float)x.y, sc[5], sh[5]);
            x = bch2(a.w); acc[6] += bnr((float)x.x, sc[6], sh[6]);  acc[7] += bnr((float)x.y, sc[7], sh[7]);
            x = bch2(b.x); acc[8] += bnr((float)x.x, sc[8], sh[8]);  acc[9] += bnr((float)x.y, sc[9], sh[9]);
            x = bch2(b.y); acc[10] += bnr((float)x.x, sc[10], sh[10]); acc[11] += bnr((float)x.y, sc[11], sh[11]);
            x = bch2(b.z); acc[12] += bnr((float)x.x, sc[12], sh[12]); acc[13] += bnr((float)x.y, sc[13], sh[13]);
            x = bch2(b.w); acc[14] += bnr((float)x.x, sc[14], sh[14]); acc[15] += bnr((float)x.y, sc[15], sh[15]);
        }
    }

    #pragma unroll
    for (int c = 0; c < 16; ++c) {
        #pragma unroll
        for (int m = 32; m >= 1; m >>= 1) acc[c] += __shfl_xor(acc[c], m);
    }
    __shared__ float sred[4][16];
    const int lane = threadIdx.x & 63;
    const int wid = threadIdx.x >> 6;
    if (lane == 0) {
        #pragma unroll
        for (int c = 0; c < 16; ++c) sred[wid][c] = acc[c];
    }
    __syncthreads();
    if (threadIdx.x < 16) {
        float tot = sred[0][threadIdx.x] + sred[1][threadIdx.x] + sred[2][threadIdx.x] + sred[3][threadIdx.x];
        atomicAdd(&bsum[((size_t)s * bs + batch) * 16 + threadIdx.x], tot);
    }
}

// ---------------- head ----------------

__global__ void final_kernel(const float* __restrict__ bsum,
                             const float* __restrict__ Wg, const float* __restrict__ bg,
                             const float* __restrict__ Wr, const float* __restrict__ br,
                             float* __restrict__ out, int bs, float invP)
{
    const int t = threadIdx.x;
    const int total = 4 * bs * 3;
    if (t < total) {
        const int x = t % 3;
        const int b = (t / 3) % bs;
        const int r = t / (3 * bs);
        const int s = r & 1;
        const float* W = (r < 2) ? Wg : Wr;
        const float* bias = (r < 2) ? bg : br;
        const float* m = bsum + ((size_t)s * bs + b) * 16;
        float a = bias[x];
        #pragma unroll
        for (int c = 0; c < 16; ++c) a = fmaf(m[c] * invP, W[c * 3 + x], a);
        out[t] = a;
    }
}

// ---------------- launch ----------------

extern "C" void kernel_launch(void* const* d_in, const int* in_sizes, int n_in,
                              void* d_out, int out_size, void* d_ws, size_t ws_size,
                              hipStream_t stream)
{
    (void)n_in; (void)ws_size;
    const float* vf0 = (const float*)d_in[0];
    const int*   nb0 = (const int*)d_in[1];
    const int*   id0 = (const int*)d_in[2];
    const float* vf1 = (const float*)d_in[3];
    const int*   nb1 = (const int*)d_in[4];
    const int*   id1 = (const int*)d_in[5];
    const float* W1 = (const float*)d_in[7];
    const float* g1 = (const float*)d_in[8];
    const float* b1 = (const float*)d_in[9];
    const float* W2 = (const float*)d_in[10];
    const float* g2 = (const float*)d_in[11];
    const float* b2 = (const float*)d_in[12];
    const float* W3 = (const float*)d_in[13];
    const float* g3 = (const float*)d_in[14];
    const float* b3 = (const float*)d_in[15];
    const float* Wg = (const float*)d_in[16];
    const float* bg = (const float*)d_in[17];
    const float* Wr = (const float*)d_in[18];
    const float* br = (const float*)d_in[19];

    const int N = in_sizes[0] / 6;       // 120000
    const int npts = in_sizes[2];        // bs * P
    const int bs = out_size / 12;        // out = [4, bs, 3]
    const int Ppb = npts / bs;
    const int Np1 = N + 1;

    const int nblk = (N + 255) / 256;    // conv blocks per stream (VPT=1)

    // workspace layout (halves / floats)
    char* ws = (char*)d_ws;
    _Float16* fin = (_Float16*)ws;                       // 2*(N+1)*8
    _Float16* w1t = fin + 2 * (size_t)Np1 * 8;           // 3456
    _Float16* w2t = w1t + 3456;                          // 13824
    _Float16* w3t = w2t + 13824;                         // 13824
    _Float16* B1  = w3t + 13824;                         // 2*(N+1)*16  (pre1, reused pre3)
    _Float16* B2  = B1 + 2 * (size_t)Np1 * 16;           // 2*(N+1)*16  (post1)
    _Float16* B3  = B2 + 2 * (size_t)Np1 * 16;           // 2*(N+1)*32  (pre2)
    _Float16* B4  = B3 + 2 * (size_t)Np1 * 32;           // 2*(N+1)*32  (post2)
    float* partials = (float*)(B4 + 2 * (size_t)Np1 * 32);  // 2*nblk*64
    float* ssb  = partials + 2 * (size_t)nblk * 64;      // 128
    float* bsum = ssb + 128;                             // 2*bs*16

    prep_feats_kernel<<<dim3((Np1 + 255) / 256, 2), 256, 0, stream>>>(vf0, vf1, fin, N);
    prep_weights_kernel<<<4, 256, 0, stream>>>(W1, W2, W3, w1t, w2t, w3t, bsum, 2 * bs * 16);

    dim3 cg(nblk, 2);
    conv_kernel<8, 16><<<cg, 256, 0, stream>>>(fin, nb0, nb1, w1t, B1, partials, N, nblk);
    stats_kernel<16><<<dim3(1, 2), 256, 0, stream>>>(partials, nblk, N, g1, b1, ssb);
    apply_kernel<16><<<dim3((Np1 * 16 / 8 + 255) / 256, 2), 256, 0, stream>>>(B1, B2, ssb, N);

    conv_kernel<16, 32><<<cg, 256, 0, stream>>>(B2, nb0, nb1, w2t, B3, partials, N, nblk);
    stats_kernel<32><<<dim3(1, 2), 256, 0, stream>>>(partials, nblk, N, g2, b2, ssb);
    apply_kernel<32><<<dim3((Np1 * 32 / 8 + 255) / 256, 2), 256, 0, stream>>>(B3, B4, ssb, N);

    conv_kernel<32, 16><<<cg, 256, 0, stream>>>(B4, nb0, nb1, w3t, B1, partials, N, nblk);
    stats_kernel<16><<<dim3(1, 2), 256, 0, stream>>>(partials, nblk, N, g3, b3, ssb);

    const int bpb = (Ppb + 2047) / 2048;
    pointsum_kernel<<<dim3(bpb * bs, 2), 256, 0, stream>>>(B1, id0, id1, ssb, bsum, N, Ppb, bpb, bs);
    final_kernel<<<1, 64, 0, stream>>>(bsum, Wg, bg, Wr, br, (float*)d_out, bs, 1.0f / Ppb);
}

// Round 4
// 616.596 us; speedup vs baseline: 1.1084x; 1.1084x over previous
//
#include <hip/hip_runtime.h>

// Sparse UNet, fp16, L2-resident gather version.
//  - stream->XCD partition: bid%8 round-robins XCDs; s=(bid>>2)&1 pins each
//    stream's gather table to 4 XCDs -> per-XCD footprint halves.
//  - conv3 input channel-split into two 16-ch arrays; two k-loop passes with
//    register accumulation -> random-gather working set always <= 3.84 MB/stream.
//  - nontemporal loads for neighbor indices, nontemporal stores for outputs
//    (streaming traffic must not evict the gather table from L2).
//  - BN stats from conv partials; BN+ReLU applied in streaming apply pass.
//  - head is linear => only per-batch channel sums of h3.

#define DEVI __device__ __forceinline__

typedef _Float16 h2 __attribute__((ext_vector_type(2)));
typedef unsigned u4 __attribute__((ext_vector_type(4)));

constexpr int KNBR = 27;

DEVI h2 bch2(unsigned u) { return __builtin_bit_cast(h2, u); }
DEVI unsigned pkh2(float a, float b) {
    h2 v; v.x = (_Float16)a; v.y = (_Float16)b;
    return __builtin_bit_cast(unsigned, v);
}
DEVI float bnr(float x, float sc, float sh) {
    float y = fmaf(x, sc, sh);
    return y > 0.f ? y : 0.f;
}

// ---------------- prep ----------------

// b0: W1 [k][6][16] -> [k][16][8];  b1: W2 [k][16][32] -> [k][32][16];
// b2: W3 [k][32][16] -> [ph][k][16][16];  b3: zero bsum
__global__ __launch_bounds__(256)
void prep_weights_kernel(const float* __restrict__ W1, const float* __restrict__ W2,
                         const float* __restrict__ W3,
                         _Float16* __restrict__ w1t, _Float16* __restrict__ w2t,
                         _Float16* __restrict__ w3t,
                         float* __restrict__ bsum, int nb)
{
    const int b = blockIdx.x;
    if (b == 3) {
        for (int i = threadIdx.x; i < nb; i += 256) bsum[i] = 0.f;
        return;
    }
    if (b == 0) {
        for (int i = threadIdx.x; i < KNBR * 16 * 8; i += 256) {
            const int c = i % 8, d = (i / 8) % 16, k = i / 128;
            w1t[i] = (_Float16)((c < 6) ? W1[(k * 6 + c) * 16 + d] : 0.f);
        }
    } else if (b == 1) {
        for (int i = threadIdx.x; i < KNBR * 32 * 16; i += 256) {
            const int c = i % 16, d = (i / 16) % 32, k = i / 512;
            w2t[i] = (_Float16)W2[(k * 16 + c) * 32 + d];
        }
    } else {
        for (int i = threadIdx.x; i < 2 * KNBR * 16 * 16; i += 256) {
            const int c = i % 16, d = (i / 16) % 16, k = (i / 256) % KNBR, ph = i / (256 * KNBR);
            w3t[i] = (_Float16)W3[(k * 32 + ph * 16 + c) * 16 + d];
        }
    }
}

// fp32 [N][6] -> fp16 [N+1][8] (pad channels, zero row N)
__global__ __launch_bounds__(256)
void prep_feats_kernel(const float* __restrict__ f0, const float* __restrict__ f1,
                       _Float16* __restrict__ o, int N)
{
    const int s = blockIdx.y;
    const float* __restrict__ f = s ? f1 : f0;
    _Float16* __restrict__ out = o + (size_t)s * (N + 1) * 8;
    const int n = blockIdx.x * 256 + threadIdx.x;
    if (n < N) {
        const float2* r = (const float2*)(f + (size_t)n * 6);
        float2 a = r[0], b = r[1], c = r[2];
        u4 w;
        w.x = pkh2(a.x, a.y);
        w.y = pkh2(b.x, b.y);
        w.z = pkh2(c.x, c.y);
        w.w = 0u;
        ((u4*)out)[n] = w;
    } else if (n == N) {
        ((u4*)out)[n] = (u4){0u, 0u, 0u, 0u};
    }
}

// ---------------- conv (gather + dot2), VPT=2, stream->XCD partitioned ----------------

template<int CINH, int COUT, int PHASES>
__global__ __launch_bounds__(256)
void conv_kernel(const _Float16* __restrict__ feats,   // [PHASES][2][(N+1)*CINH] post-BN fp16
                 const int* __restrict__ nb0, const int* __restrict__ nb1,
                 const _Float16* __restrict__ Wt,      // [PHASES][27][COUT][CINH] fp16
                 _Float16* __restrict__ outp,          // [2][(N+1)*COUT] pre-BN fp16
                 float* __restrict__ partials,
                 int N, int B)
{
    constexpr int C8 = CINH / 8;
    constexpr int WSZ = PHASES * KNBR * COUT * CINH;
    const int bid = blockIdx.x;
    const int s = (bid >> 2) & 1;                 // XCD partition: bid%8 in {0..3}->s0, {4..7}->s1
    const int vb = (bid >> 3) * 4 + (bid & 3);
    if (vb >= B) return;

    __shared__ __align__(16) _Float16 wl[WSZ];
    __shared__ float sred[4][64];
    for (int i = threadIdx.x; i < WSZ / 8; i += 256)
        ((u4*)wl)[i] = ((const u4*)Wt)[i];
    __syncthreads();
    const u4* wl4 = (const u4*)wl;

    const int tid = threadIdx.x;
    const size_t stride = (size_t)N + 1;
    const int n0 = vb * 512 + tid;
    const int n1 = n0 + 256;
    const bool a0 = n0 < N, a1 = n1 < N;
    const int* __restrict__ nbr = s ? nb1 : nb0;
    _Float16* __restrict__ out = outp + (size_t)s * stride * COUT;

    float acc0[COUT], acc1[COUT];
    #pragma unroll
    for (int d = 0; d < COUT; ++d) { acc0[d] = 0.f; acc1[d] = 0.f; }

    #pragma unroll
    for (int ph = 0; ph < PHASES; ++ph) {
        const _Float16* __restrict__ fs = feats + (size_t)(ph * 2 + s) * stride * CINH;
        const u4* __restrict__ wp = wl4 + ph * (KNBR * COUT * C8);
        int c0 = a0 ? __builtin_nontemporal_load(nbr + (size_t)n0 * KNBR) : N;
        int c1 = a1 ? __builtin_nontemporal_load(nbr + (size_t)n1 * KNBR) : N;
        for (int k = 0; k < KNBR; ++k) {
            const int kn = (k + 1 < KNBR) ? k + 1 : KNBR - 1;
            const int x0 = a0 ? __builtin_nontemporal_load(nbr + (size_t)n0 * KNBR + kn) : N;
            const int x1 = a1 ? __builtin_nontemporal_load(nbr + (size_t)n1 * KNBR + kn) : N;

            const u4* r0 = (const u4*)(fs + (size_t)c0 * CINH);
            const u4* r1 = (const u4*)(fs + (size_t)c1 * CINH);
            u4 g0[C8], g1[C8];
            #pragma unroll
            for (int c8 = 0; c8 < C8; ++c8) { g0[c8] = r0[c8]; g1[c8] = r1[c8]; }

            #pragma unroll
            for (int d = 0; d < COUT; ++d) {
                #pragma unroll
                for (int c8 = 0; c8 < C8; ++c8) {
                    const u4 wv = wp[(k * COUT + d) * C8 + c8];
                    acc0[d] = __builtin_amdgcn_fdot2(bch2(g0[c8].x), bch2(wv.x), acc0[d], false);
                    acc0[d] = __builtin_amdgcn_fdot2(bch2(g0[c8].y), bch2(wv.y), acc0[d], false);
                    acc0[d] = __builtin_amdgcn_fdot2(bch2(g0[c8].z), bch2(wv.z), acc0[d], false);
                    acc0[d] = __builtin_amdgcn_fdot2(bch2(g0[c8].w), bch2(wv.w), acc0[d], false);
                    acc1[d] = __builtin_amdgcn_fdot2(bch2(g1[c8].x), bch2(wv.x), acc1[d], false);
                    acc1[d] = __builtin_amdgcn_fdot2(bch2(g1[c8].y), bch2(wv.y), acc1[d], false);
                    acc1[d] = __builtin_amdgcn_fdot2(bch2(g1[c8].z), bch2(wv.z), acc1[d], false);
                    acc1[d] = __builtin_amdgcn_fdot2(bch2(g1[c8].w), bch2(wv.w), acc1[d], false);
                }
            }
            c0 = x0; c1 = x1;
        }
    }

    if (a0) {
        unsigned ow[COUT / 2];
        #pragma unroll
        for (int d2 = 0; d2 < COUT / 2; ++d2) ow[d2] = pkh2(acc0[2 * d2], acc0[2 * d2 + 1]);
        u4* orow = (u4*)(out + (size_t)n0 * COUT);
        #pragma unroll
        for (int q = 0; q < COUT / 8; ++q) {
            u4 v = {ow[4 * q], ow[4 * q + 1], ow[4 * q + 2], ow[4 * q + 3]};
            __builtin_nontemporal_store(v, orow + q);
        }
    }
    if (a1) {
        unsigned ow[COUT / 2];
        #pragma unroll
        for (int d2 = 0; d2 < COUT / 2; ++d2) ow[d2] = pkh2(acc1[2 * d2], acc1[2 * d2 + 1]);
        u4* orow = (u4*)(out + (size_t)n1 * COUT);
        #pragma unroll
        for (int q = 0; q < COUT / 8; ++q) {
            u4 v = {ow[4 * q], ow[4 * q + 1], ow[4 * q + 2], ow[4 * q + 3]};
            __builtin_nontemporal_store(v, orow + q);
        }
    }

    // BN statistics
    float ts[COUT], tq[COUT];
    #pragma unroll
    for (int d = 0; d < COUT; ++d) {
        ts[d] = acc0[d] + acc1[d];
        tq[d] = acc0[d] * acc0[d] + acc1[d] * acc1[d];
    }
    #pragma unroll
    for (int d = 0; d < COUT; ++d) {
        #pragma unroll
        for (int m = 32; m >= 1; m >>= 1) {
            ts[d] += __shfl_xor(ts[d], m);
            tq[d] += __shfl_xor(tq[d], m);
        }
    }
    const int lane = tid & 63;
    const int wid = tid >> 6;
    if (lane == 0) {
        #pragma unroll
        for (int d = 0; d < COUT; ++d) {
            sred[wid][d] = ts[d];
            sred[wid][COUT + d] = tq[d];
        }
    }
    __syncthreads();
    if (tid < 2 * COUT) {
        float tot = sred[0][tid] + sred[1][tid] + sred[2][tid] + sred[3][tid];
        partials[((size_t)s * B + vb) * 64 + tid] = tot;
    }
}

// ---------------- BN stats -> scale/shift ----------------

template<int COUT>
__global__ __launch_bounds__(256)
void stats_kernel(const float* __restrict__ partials, int B, int N,
                  const float* __restrict__ g, const float* __restrict__ b,
                  float* __restrict__ ss)
{
    const int s = blockIdx.y;
    const int tid = threadIdx.x;
    const float* P = partials + (size_t)s * B * 64;
    const int q = tid & 63;
    const int ch = tid >> 6;
    float a = 0.f;
    for (int i = ch; i < B; i += 4) a += P[(size_t)i * 64 + q];
    __shared__ float red[256];
    red[tid] = a;
    __syncthreads();
    if (tid < 64) red[tid] = red[tid] + red[64 + tid] + red[128 + tid] + red[192 + tid];
    __syncthreads();
    if (tid < COUT) {
        float sum = red[tid];
        float sq = red[COUT + tid];
        float mean = sum / (float)N;
        float var = sq / (float)N - mean * mean;
        float scl = g[tid] * rsqrtf(var + 1e-4f);
        float sft = b[tid] - mean * scl;
        float* ssp = ss + s * 64;
        ssp[tid] = scl;
        ssp[32 + tid] = sft;
    }
}

// ---------------- apply BN+ReLU (streaming; optional channel-split output) ----------------

template<int COUT, bool SPLIT>
__global__ __launch_bounds__(256)
void apply_kernel(const _Float16* __restrict__ pre, _Float16* __restrict__ post,
                  const float* __restrict__ ss, int N)
{
    const int s = blockIdx.y;
    const size_t stride = (size_t)N + 1;
    const _Float16* __restrict__ p = pre + (size_t)s * stride * COUT;
    __shared__ float sc[32], sh[32];
    if (threadIdx.x < COUT) {
        sc[threadIdx.x] = ss[s * 64 + threadIdx.x];
        sh[threadIdx.x] = ss[s * 64 + 32 + threadIdx.x];
    }
    __syncthreads();
    const int chunks = (int)(stride * COUT / 8);
    const int i = blockIdx.x * 256 + threadIdx.x;
    if (i >= chunks) return;
    const int row = (int)(((long long)i * 8) / COUT);
    const int cb = (i * 8) % COUT;
    u4 v = __builtin_nontemporal_load(((const u4*)p) + i);
    u4 r;
    {
        h2 x0 = bch2(v.x), x1 = bch2(v.y), x2 = bch2(v.z), x3 = bch2(v.w);
        r.x = pkh2(bnr((float)x0.x, sc[cb + 0], sh[cb + 0]),
                   bnr((float)x0.y, sc[cb + 1], sh[cb + 1]));
        r.y = pkh2(bnr((float)x1.x, sc[cb + 2], sh[cb + 2]),
                   bnr((float)x1.y, sc[cb + 3], sh[cb + 3]));
        r.z = pkh2(bnr((float)x2.x, sc[cb + 4], sh[cb + 4]),
                   bnr((float)x2.y, sc[cb + 5], sh[cb + 5]));
        r.w = pkh2(bnr((float)x3.x, sc[cb + 6], sh[cb + 6]),
                   bnr((float)x3.y, sc[cb + 7], sh[cb + 7]));
    }
    if (row >= N) r = (u4){0u, 0u, 0u, 0u};
    size_t dsti;
    if constexpr (SPLIT) {
        const int ph = cb >> 4;
        const int col = cb & 15;
        dsti = ((size_t)(ph * 2 + s) * stride * 16 + (size_t)row * 16 + col) / 8;
    } else {
        dsti = (size_t)s * stride * COUT / 8 + i;
    }
    __builtin_nontemporal_store(r, ((u4*)post) + dsti);
}

// ---------------- point gather + per-batch channel sums (BN3 inline) ----------------

__global__ __launch_bounds__(256)
void pointsum_kernel(const _Float16* __restrict__ h3,  // [2][(N+1)*16] pre-BN fp16
                     const int* __restrict__ id0, const int* __restrict__ id1,
                     const float* __restrict__ ss, float* __restrict__ bsum,
                     int N, int Ppb, int bpb, int bs, int PB)
{
    const int bid = blockIdx.x;
    const int s = (bid >> 2) & 1;
    const int pb = (bid >> 3) * 4 + (bid & 3);
    if (pb >= PB) return;
    const int batch = pb / bpb;
    const int blk = pb % bpb;

    const _Float16* __restrict__ h = h3 + (size_t)s * (N + 1) * 16;
    const int* __restrict__ ids = s ? id1 : id0;

    const float* ssp = ss + s * 64;
    float sc[16], sh[16];
    #pragma unroll
    for (int c = 0; c < 16; ++c) { sc[c] = ssp[c]; sh[c] = ssp[32 + c]; }

    float acc[16];
    #pragma unroll
    for (int c = 0; c < 16; ++c) acc[c] = 0.f;

    const int* bid_p = ids + (size_t)batch * Ppb;
    const int base = blk * (256 * 8) + threadIdx.x;
    for (int i = 0; i < 8; ++i) {
        int off = base + i * 256;
        if (off < Ppb) {
            int vx = __builtin_nontemporal_load(bid_p + off);
            const u4* r = (const u4*)(h + (size_t)vx * 16);
            u4 a = r[0], b = r[1];
            h2 x;
            x = bch2(a.x); acc[0] += bnr((float)x.x, sc[0], sh[0]);  acc[1] += bnr((float)x.y, sc[1], sh[1]);
            x = bch2(a.y); acc[2] += bnr((float)x.x, sc[2], sh[2]);  acc[3] += bnr((float)x.y, sc[3], sh[3]);
            x = bch2(a.z); acc[4] += bnr((float)x.x, sc[4], sh[4]);  acc[5] += bnr((float)x.y, sc[5], sh[5]);
            x = bch2(a.w); acc[6] += bnr((float)x.x, sc[6], sh[6]);  acc[7] += bnr((float)x.y, sc[7], sh[7]);
            x = bch2(b.x); acc[8] += bnr((float)x.x, sc[8], sh[8]);  acc[9] += bnr((float)x.y, sc[9], sh[9]);
            x = bch2(b.y); acc[10] += bnr((float)x.x, sc[10], sh[10]); acc[11] += bnr((float)x.y, sc[11], sh[11]);
            x = bch2(b.z); acc[12] += bnr((float)x.x, sc[12], sh[12]); acc[13] += bnr((float)x.y, sc[13], sh[13]);
            x = bch2(b.w); acc[14] += bnr((float)x.x, sc[14], sh[14]); acc[15] += bnr((float)x.y, sc[15], sh[15]);
        }
    }

    #pragma unroll
    for (int c = 0; c < 16; ++c) {
        #pragma unroll
        for (int m = 32; m >= 1; m >>= 1) acc[c] += __shfl_xor(acc[c], m);
    }
    __shared__ float sred[4][16];
    const int lane = threadIdx.x & 63;
    const int wid = threadIdx.x >> 6;
    if (lane == 0) {
        #pragma unroll
        for (int c = 0; c < 16; ++c) sred[wid][c] = acc[c];
    }
    __syncthreads();
    if (threadIdx.x < 16) {
        float tot = sred[0][threadIdx.x] + sred[1][threadIdx.x] + sred[2][threadIdx.x] + sred[3][threadIdx.x];
        atomicAdd(&bsum[((size_t)s * bs + batch) * 16 + threadIdx.x], tot);
    }
}

// ---------------- head ----------------

__global__ void final_kernel(const float* __restrict__ bsum,
                             const float* __restrict__ Wg, const float* __restrict__ bg,
                             const float* __restrict__ Wr, const float* __restrict__ br,
                             float* __restrict__ out, int bs, float invP)
{
    const int t = threadIdx.x;
    const int total = 4 * bs * 3;
    if (t < total) {
        const int x = t % 3;
        const int b = (t / 3) % bs;
        const int r = t / (3 * bs);
        const int s = r & 1;
        const float* W = (r < 2) ? Wg : Wr;
        const float* bias = (r < 2) ? bg : br;
        const float* m = bsum + ((size_t)s * bs + b) * 16;
        float a = bias[x];
        #pragma unroll
        for (int c = 0; c < 16; ++c) a = fmaf(m[c] * invP, W[c * 3 + x], a);
        out[t] = a;
    }
}

// ---------------- launch ----------------

extern "C" void kernel_launch(void* const* d_in, const int* in_sizes, int n_in,
                              void* d_out, int out_size, void* d_ws, size_t ws_size,
                              hipStream_t stream)
{
    (void)n_in; (void)ws_size;
    const float* vf0 = (const float*)d_in[0];
    const int*   nb0 = (const int*)d_in[1];
    const int*   id0 = (const int*)d_in[2];
    const float* vf1 = (const float*)d_in[3];
    const int*   nb1 = (const int*)d_in[4];
    const int*   id1 = (const int*)d_in[5];
    const float* W1 = (const float*)d_in[7];
    const float* g1 = (const float*)d_in[8];
    const float* b1 = (const float*)d_in[9];
    const float* W2 = (const float*)d_in[10];
    const float* g2 = (const float*)d_in[11];
    const float* b2 = (const float*)d_in[12];
    const float* W3 = (const float*)d_in[13];
    const float* g3 = (const float*)d_in[14];
    const float* b3 = (const float*)d_in[15];
    const float* Wg = (const float*)d_in[16];
    const float* bg = (const float*)d_in[17];
    const float* Wr = (const float*)d_in[18];
    const float* br = (const float*)d_in[19];

    const int N = in_sizes[0] / 6;       // 120000
    const int npts = in_sizes[2];        // bs * P
    const int bs = out_size / 12;        // out = [4, bs, 3]
    const int Ppb = npts / bs;
    const size_t Np1 = (size_t)N + 1;

    const int B = (N + 511) / 512;       // voxel blocks per stream (VPT=2, 256 thr)
    const int B4 = ((B + 3) / 4) * 4;

    // workspace layout (in halves):
    //  B_a [2][(N+1)*32] : pre1 (first half), then pre2
    //  B_b [2][(N+1)*32] : post1 (first half), then post2 channel-split [2][2][(N+1)*16]
    //  B_c [2][(N+1)*16] : fin (conv1 input, first 3.84MB), then pre3
    _Float16* B_a = (_Float16*)d_ws;
    _Float16* B_b = B_a + 2 * Np1 * 32;
    _Float16* B_c = B_b + 2 * Np1 * 32;
    _Float16* w1t = B_c + 2 * Np1 * 16;                 // 3456 halves
    _Float16* w2t = w1t + KNBR * 16 * 8;                // 13824
    _Float16* w3t = w2t + KNBR * 32 * 16;               // 13824
    float* partials = (float*)(w3t + 2 * KNBR * 16 * 16);  // 2*B*64
    float* ssb  = partials + 2 * (size_t)B * 64;        // 128
    float* bsum = ssb + 128;                            // 2*bs*16

    _Float16* fin = B_c;

    prep_feats_kernel<<<dim3((unsigned)((Np1 + 255) / 256), 2), 256, 0, stream>>>(vf0, vf1, fin, N);
    prep_weights_kernel<<<4, 256, 0, stream>>>(W1, W2, W3, w1t, w2t, w3t, bsum, 2 * bs * 16);

    // conv1: fin -> pre1 (B_a)
    conv_kernel<8, 16, 1><<<2 * B4, 256, 0, stream>>>(fin, nb0, nb1, w1t, B_a, partials, N, B);
    stats_kernel<16><<<dim3(1, 2), 256, 0, stream>>>(partials, B, N, g1, b1, ssb);
    apply_kernel<16, false><<<dim3((unsigned)((Np1 * 16 / 8 + 255) / 256), 2), 256, 0, stream>>>(B_a, B_b, ssb, N);

    // conv2: post1 (B_b) -> pre2 (B_a)
    conv_kernel<16, 32, 1><<<2 * B4, 256, 0, stream>>>(B_b, nb0, nb1, w2t, B_a, partials, N, B);
    stats_kernel<32><<<dim3(1, 2), 256, 0, stream>>>(partials, B, N, g2, b2, ssb);
    apply_kernel<32, true><<<dim3((unsigned)((Np1 * 32 / 8 + 255) / 256), 2), 256, 0, stream>>>(B_a, B_b, ssb, N);

    // conv3: post2 split (B_b) -> pre3 (B_c)
    conv_kernel<16, 16, 2><<<2 * B4, 256, 0, stream>>>(B_b, nb0, nb1, w3t, B_c, partials, N, B);
    stats_kernel<16><<<dim3(1, 2), 256, 0, stream>>>(partials, B, N, g3, b3, ssb);

    const int bpb = (Ppb + 2047) / 2048;
    const int PB = bpb * bs;
    const int PB4 = ((PB + 3) / 4) * 4;
    pointsum_kernel<<<2 * PB4, 256, 0, stream>>>(B_c, id0, id1, ssb, bsum, N, Ppb, bpb, bs, PB);
    final_kernel<<<1, 64, 0, stream>>>(bsum, Wg, bg, Wr, br, (float*)d_out, bs, 1.0f / Ppb);
}